// Round 8
// baseline (1867.405 us; speedup 1.0000x reference)
//
#include <hip/hip_runtime.h>

typedef unsigned short u16;
typedef __attribute__((ext_vector_type(8))) short frag8;
typedef __attribute__((ext_vector_type(4))) float f32x4;
typedef __attribute__((ext_vector_type(8))) unsigned short u16x8;

// address-space typedefs for global_load_lds
typedef __attribute__((address_space(1))) const void GV;
typedef __attribute__((address_space(3))) void LV;

__device__ __forceinline__ void gl16(const u16* g, u16* l) {
  // async global->LDS, 16B per lane; LDS dest = wave-uniform base + lane*16
  __builtin_amdgcn_global_load_lds((GV*)g, (LV*)l, 16, 0, 0);
}

__device__ __forceinline__ float b2f(u16 u) {
  union { unsigned int i; float f; } v; v.i = ((unsigned int)u) << 16; return v.f;
}
__device__ __forceinline__ u16 f2b(float f) {
  union { float f; unsigned int i; } v; v.f = f;
  unsigned int x = v.i;
  x += 0x7fffu + ((x >> 16) & 1u);
  return (u16)(x >> 16);
}
// fast tanh: 1 - 2/(e^{2x}+1). Large +x: e=inf -> 1; large -x: e=0 -> -1.
__device__ __forceinline__ float ftanh(float x) {
  float e = __expf(2.f * x);
  return 1.f - 2.f / (e + 1.f);
}

// ---------------------------------------------------------------------------
// XCD-aware blockIdx remap (T1, m204 bijective form). axis 0: each XCD owns a
// contiguous x-range (B-slice fits its 4MB L2). axis 1: contiguous y-range.
// Perf-only bijection.
// ---------------------------------------------------------------------------
__device__ __forceinline__ void xcd_remap(int axis, int& bx, int& by) {
  const int nx = gridDim.x, ny = gridDim.y;
  const int nwg = nx * ny;
  const int bid = blockIdx.x + nx * blockIdx.y;
  const int q = nwg >> 3, r = nwg & 7;
  const int xcd = bid & 7, i = bid >> 3;
  const int rem = (xcd < r ? xcd * (q + 1) : r * (q + 1) + (xcd - r) * q) + i;
  if (axis == 0) { bx = rem / ny; by = rem - bx * ny; }
  else           { by = rem / nx; bx = rem - by * nx; }
}

// ---------------------------------------------------------------------------
// One-shot prep: every bf16 conversion + the prev matrix P, in ONE dispatch.
// P[32768][192]: row = t*2048 + e*128 + b, tt = e*16 + t;
// P[row][k] = (tt>0 && k<130) ? target[b][tt-1][k] : 0.
// ---------------------------------------------------------------------------
__global__ void mega_prep(const float* __restrict__ c, const float* __restrict__ fiw,
                          const float* __restrict__ g1whh, const float* __restrict__ g2wih,
                          const float* __restrict__ g2whh, const float* __restrict__ g1wih,
                          const float* __restrict__ fcow, const float* __restrict__ target,
                          u16* __restrict__ cbf, u16* __restrict__ Wfi, u16* __restrict__ W1h,
                          u16* __restrict__ W2i, u16* __restrict__ W2h, u16* __restrict__ Wc,
                          u16* __restrict__ Wd, u16* __restrict__ WBy, u16* __restrict__ P)
{
  int i = blockIdx.x * 256 + threadIdx.x;       // 57600 blocks x 256 = 14,745,600
  if (i < 1048576) { cbf[i] = f2b(c[i]); return; }
  i -= 1048576;
  if (i < 1048576) { Wfi[i] = f2b(fiw[i]); return; }
  i -= 1048576;
  if (i < 3145728) { W1h[i] = f2b(g1whh[i]); return; }
  i -= 3145728;
  if (i < 3145728) { W2i[i] = f2b(g2wih[i]); return; }
  i -= 3145728;
  if (i < 3145728) { W2h[i] = f2b(g2whh[i]); return; }
  i -= 3145728;
  if (i < 1572864) { int n = i >> 9, k = i & 511; Wc[i] = f2b(g1wih[n * 642 + k]); return; }
  i -= 1572864;
  if (i < 589824) {  // Wd [3072][192], zero-pad k>=130
    int n = i / 192, k = i - n * 192;
    Wd[i] = (k < 130) ? f2b(g1wih[n * 642 + 512 + k]) : (u16)0;
    return;
  }
  i -= 589824;
  if (i < 262144) { int n = i >> 10; WBy[i] = (n < 130) ? f2b(fcow[i]) : (u16)0; return; }
  i -= 262144;
  {  // P: 786432 items, 8 elems each
    int row = i / 24;
    int k0 = (i - row * 24) * 8;
    int t = row >> 11, m2 = row & 2047;
    int e = m2 >> 7, b = m2 & 127;
    int tt = e * 16 + t;
    u16x8 r;
    if (tt > 0 && k0 + 8 <= 130) {
      const float* trow = target + (size_t)(b * 256 + tt - 1) * 130 + k0;
#pragma unroll
      for (int q = 0; q < 8; ++q) r[q] = f2b(trow[q]);
    } else if (tt > 0 && k0 < 130) {
      const float* trow = target + (size_t)(b * 256 + tt - 1) * 130;
#pragma unroll
      for (int q = 0; q < 8; ++q) { int k = k0 + q; r[q] = (k < 130) ? f2b(trow[k]) : (u16)0; }
    } else {
#pragma unroll
      for (int q = 0; q < 8; ++q) r[q] = (u16)0;
    }
    *(u16x8*)&P[(size_t)row * 192 + k0] = r;
  }
}

// ---------------------------------------------------------------------------
// GEMM core r14: **256x128 block tile**, BK=32, 512 threads = 8 waves
// (4m x 2n), **wave tile 64x64 = 4x4 acc** of mfma 16x16x32 bf16.
// r13 analysis: at the old 32x64 wave tile, LDS served 768 B/MFMA (6 b128
// reads per 8 MFMAs) -> LDS pipe = ~2100 of 3250 cyc/K-step = the 533 TF
// plateau. Now 8 b128 -> 16 MFMA = 512 B/MFMA, and intensity rises
// 64 -> 85 FLOP/B (L3 ceiling 531 -> ~708 TF). 8 waves kept (r10's failure
// was 4 waves = no latency hiding, NOT the 4x4 acc itself).
// LDS 72KB (A 3x16KB + B 3x8KB) -> 2 blocks/CU, 16 waves.
// K-loop: 3-buffer counted-vmcnt; 3 gl16/wave/tile (A rows w*32..+32 via 2,
// B rows w*16..+16 via 1) -> vmcnt(3). Same rotation/hazard logic as r9-r13
// (buf (ks+2)%3 last read iter ks-1; iter-ks barrier orders it).
// Swizzle unchanged: chunk' = chunk ^ ((row>>1)&3); staging scol uses
// (lane>>3)&3 == (row_in_slab>>1)&3 (slab bases are multiples of 16 rows,
// wave tiles multiples of 64 -> invariance holds for A and B). 0 conflicts.
// ---------------------------------------------------------------------------
__device__ __forceinline__ void kloop3(
    const u16* gA, int lda, const u16* gB, int nk,
    u16* AsBase, u16* BsBase, int wave,
    int rdA, int rdB, f32x4 (&acc)[4][4])
{
  u16* Ad = AsBase + wave * 1024;   // wave A slab: 32 rows x 32 u16
  u16* Bd = BsBase + wave * 512;    // wave B slab: 16 rows x 32 u16
  const u16* gA2 = gA + (size_t)16 * lda;
  // prologue: tiles 0,1 in flight (nk >= 2 always here)
  gl16(gA,      Ad);            gl16(gA2,      Ad + 512);        gl16(gB,      Bd);
  gl16(gA + 32, Ad + 8192);     gl16(gA2 + 32, Ad + 8192 + 512); gl16(gB + 32, Bd + 4096);
  const u16* pA  = gA  + 64;
  const u16* pA2 = gA2 + 64;
  const u16* pB  = gB  + 64;
  int cbuf = 0, nbuf = 2;
  for (int ks = 0; ks < nk; ++ks) {
    if (ks < nk - 1) asm volatile("s_waitcnt vmcnt(3)" : : : "memory");
    else             asm volatile("s_waitcnt vmcnt(0)" : : : "memory");
    __builtin_amdgcn_s_barrier();
    __builtin_amdgcn_sched_barrier(0);
    if (ks + 2 < nk) {
      gl16(pA,  Ad + nbuf * 8192);
      gl16(pA2, Ad + nbuf * 8192 + 512);
      gl16(pB,  Bd + nbuf * 4096);
      pA += 32; pA2 += 32; pB += 32;
    }
    const u16* Ab = AsBase + cbuf * 8192;
    const u16* Bb = BsBase + cbuf * 4096;
    frag8 af[4], bfr[4];
#pragma unroll
    for (int i = 0; i < 4; ++i)
      af[i] = *(const frag8*)&Ab[rdA + i * 512];
#pragma unroll
    for (int j = 0; j < 4; ++j)
      bfr[j] = *(const frag8*)&Bb[rdB + j * 512];
#pragma unroll
    for (int i = 0; i < 4; ++i)
#pragma unroll
      for (int j = 0; j < 4; ++j)
        acc[i][j] = __builtin_amdgcn_mfma_f32_16x16x32_bf16(af[i], bfr[j], acc[i][j], 0, 0, 0);
    cbuf = (cbuf == 2) ? 0 : cbuf + 1;
    nbuf = (nbuf == 2) ? 0 : nbuf + 1;
  }
}

// fragment-read / staging offsets shared by all GEMM kernels
struct GeomT { int wave, lane, wm, wn, lr, lq, rdA, rdB, srowA, srowB, scol; };
__device__ __forceinline__ GeomT geom(int tid) {
  GeomT g;
  g.wave = tid >> 6; g.lane = tid & 63;
  g.wm = (g.wave & 3) * 64;    // 4 m-waves x 64 rows   (block M = 256)
  g.wn = (g.wave >> 2) * 64;   // 2 n-waves x 64 cols   (block N = 128)
  g.lr = g.lane & 15; g.lq = g.lane >> 4;
  int sw = (g.lr >> 1) & 3;
  g.rdA = (g.wm + g.lr) * 32 + ((g.lq ^ sw) << 3);
  g.rdB = (g.wn + g.lr) * 32 + ((g.lq ^ sw) << 3);
  g.srowA = g.wave * 32 + (g.lane >> 2);
  g.srowB = g.wave * 16 + (g.lane >> 2);
  g.scol = (((g.lane & 3) ^ ((g.lane >> 3) & 3)) << 3);
  return g;
}

// ---------------------------------------------------------------------------
// bt-GEMM (FALLBACK path only): modes 2/3/4. M=2048 -> grid y = 8.
// ---------------------------------------------------------------------------
__global__ __launch_bounds__(512, 4) void gemm_bt(
    const u16* __restrict__ A, int lda,
    const u16* __restrict__ B0, const u16* __restrict__ B1, int ldb, int n_split,
    int N, int K, int mode, int tstep, int axis,
    const float* __restrict__ bias0, const float* __restrict__ bias1,
    u16* __restrict__ out0, u16* __restrict__ out1,
    const u16* __restrict__ addmat,
    float* __restrict__ fout0, float* __restrict__ fout1)
{
  __shared__ u16 As[3 * 8192];
  __shared__ u16 Bs[3 * 4096];
  int bx, by; xcd_remap(axis, bx, by);
  GeomT g = geom(threadIdx.x);
  const int m0 = by * 256, n0 = bx * 128;

  const u16* Bsel; int nb0;
  if (n0 < n_split) { Bsel = B0; nb0 = n0; }
  else              { Bsel = B1; nb0 = n0 - n_split; }

  f32x4 acc[4][4] = {};
  const u16* gA = &A[(size_t)(m0 + g.srowA) * lda + g.scol];
  const u16* gB = &Bsel[(size_t)(nb0 + g.srowB) * ldb + g.scol];
  kloop3(gA, lda, gB, K >> 5, As, Bs, g.wave, g.rdA, g.rdB, acc);

#pragma unroll
  for (int i = 0; i < 4; ++i) {
#pragma unroll
    for (int r = 0; r < 4; ++r) {
      int m = m0 + g.wm + i * 16 + g.lq * 4 + r;
#pragma unroll
      for (int j = 0; j < 4; ++j) {
        int n = n0 + g.wn + j * 16 + g.lr;
        float v = acc[i][j][r];
        if (mode == 2) {
          out0[(size_t)m * 3072 + n] = f2b(v + b2f(addmat[(size_t)(m & 2047) * 3072 + n]));
        } else if (mode == 3) {
          if (n < 3072) out0[(size_t)m * 3072 + n] = f2b(v + bias0[n]);
          else          out1[(size_t)m * 3072 + (n - 3072)] = f2b(v + bias1[n - 3072]);
        } else { // mode 4
          if (n < 3072) {
            out0[(size_t)m * 3072 + n] = f2b(v + bias0[n]);
          } else if (n < 3202) {
            int d = n - 3072;
            int b = m & 127, e = m >> 7;
            fout0[(size_t)((b << 8) + (e << 4) + tstep) * 130 + d] = v + bias1[d];
          }
        }
      }
    }
  }
}

// ---------------------------------------------------------------------------
// Init GEMM A: bx<16: {h1,h2} = tanh(c@Wfi.T + fib) (f32 + bf16 shadow);
// bx in [16,40): gic = c@Wc.T + g1bih.  Both K=512, A=cbf. Grid (40, 8).
// ---------------------------------------------------------------------------
__global__ __launch_bounds__(512, 4) void gemm_A(
    const u16* __restrict__ cbf, const u16* __restrict__ Wfi, const u16* __restrict__ Wc,
    const float* __restrict__ fib, const float* __restrict__ g1bih,
    float* __restrict__ h1f, float* __restrict__ h2f,
    u16* __restrict__ h1b, u16* __restrict__ h2b, u16* __restrict__ gic)
{
  __shared__ u16 As[3 * 8192];
  __shared__ u16 Bs[3 * 4096];
  int bx, by; xcd_remap(0, bx, by);
  GeomT g = geom(threadIdx.x);
  const int m0 = by * 256;
  const int isInit = (bx < 16);
  const int nb0 = isInit ? bx * 128 : (bx - 16) * 128;
  const u16* Bw = isInit ? Wfi : Wc;

  f32x4 acc[4][4] = {};
  const u16* gA = &cbf[(size_t)(m0 + g.srowA) * 512 + g.scol];
  const u16* gB = &Bw[(size_t)(nb0 + g.srowB) * 512 + g.scol];
  kloop3(gA, 512, gB, 16, As, Bs, g.wave, g.rdA, g.rdB, acc);

#pragma unroll
  for (int i = 0; i < 4; ++i) {
#pragma unroll
    for (int r = 0; r < 4; ++r) {
      int m = m0 + g.wm + i * 16 + g.lq * 4 + r;
#pragma unroll
      for (int j = 0; j < 4; ++j) {
        int n = nb0 + g.wn + j * 16 + g.lr;
        float v = acc[i][j][r];
        if (isInit) {
          float t = ftanh(v + fib[n]);
          if (n < 1024) { h1f[(size_t)m * 1024 + n] = t;          h1b[(size_t)m * 1024 + n] = f2b(t); }
          else          { h2f[(size_t)m * 1024 + (n - 1024)] = t; h2b[(size_t)m * 1024 + (n - 1024)] = f2b(t); }
        } else {
          gic[(size_t)m * 3072 + n] = f2b(v + g1bih[n]);
        }
      }
    }
  }
}

// ---------------------------------------------------------------------------
// Init GEMM B: bx<24: gh1 = h1@W1h+b1hh | <48: gh2 = h2@W2h+b2hh |
// <72: gi1(0) = P[t=0]@Wd.T + gic (K=192). Grid (72,8); (48,8) in fallback.
// ---------------------------------------------------------------------------
__global__ __launch_bounds__(512, 4) void gemm_B(
    const u16* __restrict__ h1b, const u16* __restrict__ h2b, const u16* __restrict__ P,
    const u16* __restrict__ W1h, const u16* __restrict__ W2h, const u16* __restrict__ Wd,
    const float* __restrict__ b1hh, const float* __restrict__ b2hh,
    const u16* __restrict__ gic,
    u16* __restrict__ gh1, u16* __restrict__ gh2, u16* __restrict__ gi1w)
{
  __shared__ u16 As[3 * 8192];
  __shared__ u16 Bs[3 * 4096];
  int bx, by; xcd_remap(0, bx, by);
  GeomT g = geom(threadIdx.x);
  const int m0 = by * 256;
  int reg, nb0;
  const u16 *A, *Bw; int ld, K;
  if (bx < 24)      { reg = 0; nb0 = bx * 128;        A = h1b; Bw = W1h; ld = 1024; K = 1024; }
  else if (bx < 48) { reg = 1; nb0 = (bx - 24) * 128; A = h2b; Bw = W2h; ld = 1024; K = 1024; }
  else              { reg = 2; nb0 = (bx - 48) * 128; A = P;   Bw = Wd;  ld = 192;  K = 192;  }

  f32x4 acc[4][4] = {};
  const u16* gA = &A[(size_t)(m0 + g.srowA) * ld + g.scol];
  const u16* gB = &Bw[(size_t)(nb0 + g.srowB) * ld + g.scol];
  kloop3(gA, ld, gB, K >> 5, As, Bs, g.wave, g.rdA, g.rdB, acc);

#pragma unroll
  for (int i = 0; i < 4; ++i) {
#pragma unroll
    for (int r = 0; r < 4; ++r) {
      int m = m0 + g.wm + i * 16 + g.lq * 4 + r;
#pragma unroll
      for (int j = 0; j < 4; ++j) {
        int n = nb0 + g.wn + j * 16 + g.lr;
        float v = acc[i][j][r];
        if (reg == 0)      gh1[(size_t)m * 3072 + n] = f2b(v + b1hh[n]);
        else if (reg == 1) gh2[(size_t)m * 3072 + n] = f2b(v + b2hh[n]);
        else               gi1w[(size_t)m * 3072 + n] = f2b(v + b2f(gic[(size_t)m * 3072 + n]));
      }
    }
  }
}

// ---------------------------------------------------------------------------
// Fused step GEMM with 5 regions selected by x-tile thresholds c0..c3:
//   [0,c0)   reg0 gi2  = h1@W2i + b_gi2          (K=1024)
//   [c0,c1)  reg1 gh1' = h1@W1h + b_gh1          (K=1024)
//   [c1,c2)  reg2 gh2' = h2@W2h + b_gh2          (K=1024)
//   [c2,c3)  reg3 y(tstep) = h2@WBy + fcob, f32 scatter (K=1024)
//   [c3,gx)  reg4 gi1(t+1) = Pt@Wd.T + gic       (K=192) -> rolling g1A
// Rolling g1A safe: C(t) reads strictly before G(t) overwrites (same stream).
// Configs: G(0)={24,48,48,48} gx72; G(1..14)={24,48,72,74} gx98;
// G(15)={24,24,48,50} gx50 (r13 fix: gh2(15) kept); G(16)={0,0,0,2} gx2.
// ---------------------------------------------------------------------------
__global__ __launch_bounds__(512, 4) void gemm_fused(
    const u16* __restrict__ h1b, const u16* __restrict__ h2b, const u16* __restrict__ Pt,
    const u16* __restrict__ W2i, const u16* __restrict__ W1h, const u16* __restrict__ W2h,
    const u16* __restrict__ WBy, const u16* __restrict__ Wd,
    const float* __restrict__ b_gi2, const float* __restrict__ b_gh1,
    const float* __restrict__ b_gh2, const float* __restrict__ b_y,
    const u16* __restrict__ gic,
    u16* __restrict__ gi2, u16* __restrict__ gh1, u16* __restrict__ gh2,
    float* __restrict__ y, u16* __restrict__ gi1w,
    int c0, int c1, int c2, int c3, int tstep)
{
  __shared__ u16 As[3 * 8192];
  __shared__ u16 Bs[3 * 4096];
  int bx, by; xcd_remap(0, bx, by);
  GeomT g = geom(threadIdx.x);
  const int m0 = by * 256;
  int reg, nb0;
  const u16 *A, *Bw; int ld, K;
  if (bx < c0)      { reg = 0; nb0 = bx * 128;        A = h1b; Bw = W2i; ld = 1024; K = 1024; }
  else if (bx < c1) { reg = 1; nb0 = (bx - c0) * 128; A = h1b; Bw = W1h; ld = 1024; K = 1024; }
  else if (bx < c2) { reg = 2; nb0 = (bx - c1) * 128; A = h2b; Bw = W2h; ld = 1024; K = 1024; }
  else if (bx < c3) { reg = 3; nb0 = (bx - c2) * 128; A = h2b; Bw = WBy; ld = 1024; K = 1024; }
  else              { reg = 4; nb0 = (bx - c3) * 128; A = Pt;  Bw = Wd;  ld = 192;  K = 192;  }

  f32x4 acc[4][4] = {};
  const u16* gA = &A[(size_t)(m0 + g.srowA) * ld + g.scol];
  const u16* gB = &Bw[(size_t)(nb0 + g.srowB) * ld + g.scol];
  kloop3(gA, ld, gB, K >> 5, As, Bs, g.wave, g.rdA, g.rdB, acc);

#pragma unroll
  for (int i = 0; i < 4; ++i) {
#pragma unroll
    for (int r = 0; r < 4; ++r) {
      int m = m0 + g.wm + i * 16 + g.lq * 4 + r;
#pragma unroll
      for (int j = 0; j < 4; ++j) {
        int nl = nb0 + g.wn + j * 16 + g.lr;
        float v = acc[i][j][r];
        if (reg == 0)      gi2[(size_t)m * 3072 + nl] = f2b(v + b_gi2[nl]);
        else if (reg == 1) gh1[(size_t)m * 3072 + nl] = f2b(v + b_gh1[nl]);
        else if (reg == 2) gh2[(size_t)m * 3072 + nl] = f2b(v + b_gh2[nl]);
        else if (reg == 3) {
          if (nl < 130) {
            int b = m & 127, e = m >> 7;
            y[(size_t)((b << 8) + (e << 4) + tstep) * 130 + nl] = v + b_y[nl];
          }
        } else {
          gi1w[(size_t)m * 3072 + nl] = f2b(v + b2f(gic[(size_t)m * 3072 + nl]));
        }
      }
    }
  }
}

// ---------------------------------------------------------------------------
// Fused GRU combine: slot A = combine1(t) [h1 <- GRU1], slot B =
// combine2(t-1) [h2 <- GRU2]. h = (1-z)*n + z*h; gi/gh bf16 [2048,3072]
// (biases folded), h32 f32 master state (in place), hb16 bf16 shadow.
// ---------------------------------------------------------------------------
__global__ __launch_bounds__(256) void gru2(
    const u16* __restrict__ giA, const u16* __restrict__ ghA,
    float* __restrict__ hA, u16* __restrict__ hbA,
    const u16* __restrict__ giB, const u16* __restrict__ ghB,
    float* __restrict__ hB, u16* __restrict__ hbB,
    int doA, int doB)
{
  int blk = blockIdx.x;
  const u16 *gi, *gh; float* h32; u16* hb16;
  if (blk < 1024) { if (!doA) return; gi = giA; gh = ghA; h32 = hA; hb16 = hbA; }
  else { if (!doB) return; gi = giB; gh = ghB; h32 = hB; hb16 = hbB; blk -= 1024; }
  int idx = blk * 256 + threadIdx.x;   // 0 .. 2048*128-1
  int m = idx >> 7;
  int j0 = (idx & 127) << 3;
  const size_t gb = (size_t)m * 3072 + j0;
  const size_t hb = (size_t)m * 1024 + j0;
  u16x8 ir = *(const u16x8*)&gi[gb];
  u16x8 iz = *(const u16x8*)&gi[gb + 1024];
  u16x8 in_ = *(const u16x8*)&gi[gb + 2048];
  u16x8 hr = *(const u16x8*)&gh[gb];
  u16x8 hz = *(const u16x8*)&gh[gb + 1024];
  u16x8 hn = *(const u16x8*)&gh[gb + 2048];
  f32x4 h0 = *(const f32x4*)&h32[hb];
  f32x4 h1v = *(const f32x4*)&h32[hb + 4];
  f32x4 o0, o1;
  u16x8 ob;
#pragma unroll
  for (int q = 0; q < 8; ++q) {
    float r = 1.f / (1.f + __expf(-(b2f(ir[q]) + b2f(hr[q]))));
    float z = 1.f / (1.f + __expf(-(b2f(iz[q]) + b2f(hz[q]))));
    float nn = ftanh(b2f(in_[q]) + r * b2f(hn[q]));
    float hh = (q < 4) ? h0[q & 3] : h1v[q & 3];
    float res = (1.f - z) * nn + z * hh;
    if (q < 4) o0[q & 3] = res; else o1[q & 3] = res;
    ob[q] = f2b(res);
  }
  *(f32x4*)&h32[hb] = o0;
  *(f32x4*)&h32[hb + 4] = o1;
  *(u16x8*)&hb16[hb] = ob;
}

// ---------------------------------------------------------------------------
extern "C" void kernel_launch(void* const* d_in, const int* in_sizes, int n_in,
                              void* d_out, int out_size, void* d_ws, size_t ws_size,
                              hipStream_t stream)
{
  const float* c      = (const float*)d_in[0];
  const float* target = (const float*)d_in[1];
  const float* fiw    = (const float*)d_in[4];
  const float* fib    = (const float*)d_in[5];
  const float* g1wih  = (const float*)d_in[6];
  const float* g1whh  = (const float*)d_in[7];
  const float* g1bih  = (const float*)d_in[8];
  const float* g1bhh  = (const float*)d_in[9];
  const float* g2wih  = (const float*)d_in[10];
  const float* g2whh  = (const float*)d_in[11];
  const float* g2bih  = (const float*)d_in[12];
  const float* g2bhh  = (const float*)d_in[13];
  const float* fcow   = (const float*)d_in[14];
  const float* fcob   = (const float*)d_in[15];
  float* out = (float*)d_out;

  char* wsp = (char*)d_ws;
  size_t off = 0;
  auto takeb = [&](size_t bytes) {
    void* p = (void*)(wsp + off);
    off += bytes;
    off = (off + 255) & ~(size_t)255;
    return p;
  };
  float* h1f = (float*)takeb((size_t)2048 * 1024 * 4);
  float* h2f = (float*)takeb((size_t)2048 * 1024 * 4);
  u16* h1b   = (u16*)takeb((size_t)2048 * 1024 * 2);
  u16* h2b   = (u16*)takeb((size_t)2048 * 1024 * 2);
  u16* gic   = (u16*)takeb((size_t)2048 * 3072 * 2);
  u16* gib   = (u16*)takeb((size_t)2048 * 3072 * 2);
  u16* gh1   = (u16*)takeb((size_t)2048 * 3072 * 2);
  u16* gh2   = (u16*)takeb((size_t)2048 * 3072 * 2);
  u16* cbf   = (u16*)takeb((size_t)2048 * 512 * 2);
  u16* Wfi   = (u16*)takeb((size_t)2048 * 512 * 2);
  u16* Wc    = (u16*)takeb((size_t)3072 * 512 * 2);
  u16* Wd    = (u16*)takeb((size_t)3072 * 192 * 2);
  u16* W1h   = (u16*)takeb((size_t)3072 * 1024 * 2);
  u16* W2i   = (u16*)takeb((size_t)3072 * 1024 * 2);
  u16* W2h   = (u16*)takeb((size_t)3072 * 1024 * 2);
  u16* WBy   = (u16*)takeb((size_t)256 * 1024 * 2);
  u16* P     = (u16*)takeb((size_t)32768 * 192 * 2);   // prev matrix, all t
  // base ~116 MiB. Rolling gi1 buffer (12.6 MiB) for the fast path.
  u16* g1A = nullptr;
  if (ws_size >= off + (size_t)2048 * 3072 * 2 + 256) g1A = (u16*)takeb((size_t)2048 * 3072 * 2);
  (void)in_sizes; (void)n_in; (void)out_size;

  const int BIG = 1 << 30;

  // --- prep + init ---
  mega_prep<<<57600, 256, 0, stream>>>(c, fiw, g1whh, g2wih, g2whh, g1wih, fcow, target,
                                       cbf, Wfi, W1h, W2i, W2h, Wc, Wd, WBy, P);
  gemm_A<<<dim3(40, 8), 512, 0, stream>>>(cbf, Wfi, Wc, fib, g1bih,
                                          h1f, h2f, h1b, h2b, gic);

  if (g1A != nullptr) {
    // gh1 | gh2 | gi1(0) init
    gemm_B<<<dim3(72, 8), 512, 0, stream>>>(h1b, h2b, P, W1h, W2h, Wd,
                                            g1bhh, g2bhh, gic, gh1, gh2, g1A);
    // C(0): combine1(0)
    gru2<<<2048, 256, 0, stream>>>(g1A, gh1, h1f, h1b, nullptr, nullptr, nullptr, nullptr, 1, 0);
    // G(0): gi2(0), gh1'(0->1), gi1(1)
    gemm_fused<<<dim3(72, 8), 512, 0, stream>>>(h1b, h2b, P + (size_t)1 * 2048 * 192,
                                                W2i, W1h, W2h, WBy, Wd,
                                                g2bih, g1bhh, g2bhh, fcob, gic,
                                                gib, gh1, gh2, out, g1A,
                                                24, 48, 48, 48, 0);
    for (int t = 1; t <= 14; ++t) {
      // C(t): combine1(t) [g1A, gh1] + combine2(t-1) [gib, gh2]
      gru2<<<2048, 256, 0, stream>>>(g1A, gh1, h1f, h1b, gib, gh2, h2f, h2b, 1, 1);
      // G(t): gi2(t), gh1'(t+1), gh2'(t), y(t-1), gi1(t+1)
      gemm_fused<<<dim3(98, 8), 512, 0, stream>>>(h1b, h2b, P + (size_t)(t + 1) * 2048 * 192,
                                                  W2i, W1h, W2h, WBy, Wd,
                                                  g2bih, g1bhh, g2bhh, fcob, gic,
                                                  gib, gh1, gh2, out, g1A,
                                                  24, 48, 72, 74, t - 1);
    }
    // C(15): combine1(15) + combine2(14)
    gru2<<<2048, 256, 0, stream>>>(g1A, gh1, h1f, h1b, gib, gh2, h2f, h2b, 1, 1);
    // G(15): gi2(15) + gh2(15) + y(14)
    gemm_fused<<<dim3(50, 8), 512, 0, stream>>>(h1b, h2b, P,
                                                W2i, W1h, W2h, WBy, Wd,
                                                g2bih, g1bhh, g2bhh, fcob, gic,
                                                gib, gh1, gh2, out, g1A,
                                                24, 24, 48, 50, 14);
    // C(16): combine2(15)
    gru2<<<2048, 256, 0, stream>>>(nullptr, nullptr, nullptr, nullptr,
                                   gib, gh2, h2f, h2b, 0, 1);
    // G(16): y(15) only
    gemm_fused<<<dim3(2, 8), 512, 0, stream>>>(h1b, h2b, P,
                                               W2i, W1h, W2h, WBy, Wd,
                                               g2bih, g1bhh, g2bhh, fcob, gic,
                                               gib, gh1, gh2, out, g1A,
                                               0, 0, 0, 2, 15);
  } else {
    // fallback (tiny ws): per-step sequence; gh1/gh2 init via gemm_B grid 48
    gemm_B<<<dim3(48, 8), 512, 0, stream>>>(h1b, h2b, P, W1h, W2h, Wd,
                                            g1bhh, g2bhh, gic, gh1, gh2, nullptr);
    for (int t = 0; t < 16; ++t) {
      gemm_bt<<<dim3(24, 8), 512, 0, stream>>>(P + (size_t)t * 2048 * 192, 192, Wd, nullptr, 192, BIG,
                                               3072, 192, 2, 0, 0, nullptr, nullptr,
                                               gib, nullptr, gic, nullptr, nullptr);
      gru2<<<2048, 256, 0, stream>>>(gib, gh1, h1f, h1b, nullptr, nullptr, nullptr, nullptr, 1, 0);
      gemm_bt<<<dim3(48, 8), 512, 0, stream>>>(h1b, 1024, W2i, W1h, 1024, 3072,
                                               6144, 1024, 3, 0, 0, g2bih, g1bhh,
                                               gib, gh1, nullptr, nullptr, nullptr);
      gru2<<<2048, 256, 0, stream>>>(gib, gh2, h2f, h2b, nullptr, nullptr, nullptr, nullptr, 1, 0);
      gemm_bt<<<dim3(26, 8), 512, 0, stream>>>(h2b, 1024, W2h, WBy, 1024, 3072,
                                               3328, 1024, 4, t, 0, g2bhh, fcob,
                                               gh2, nullptr, nullptr, out, nullptr);
    }
  }
}

// Round 9
// 1547.258 us; speedup vs baseline: 1.2069x; 1.2069x over previous
//
#include <hip/hip_runtime.h>

typedef unsigned short u16;
typedef __attribute__((ext_vector_type(8))) short frag8;
typedef __attribute__((ext_vector_type(4))) float f32x4;
typedef __attribute__((ext_vector_type(8))) unsigned short u16x8;

// address-space typedefs for global_load_lds
typedef __attribute__((address_space(1))) const void GV;
typedef __attribute__((address_space(3))) void LV;

__device__ __forceinline__ void gl16(const u16* g, u16* l) {
  // async global->LDS, 16B per lane; LDS dest = wave-uniform base + lane*16
  __builtin_amdgcn_global_load_lds((GV*)g, (LV*)l, 16, 0, 0);
}

__device__ __forceinline__ float b2f(u16 u) {
  union { unsigned int i; float f; } v; v.i = ((unsigned int)u) << 16; return v.f;
}
__device__ __forceinline__ u16 f2b(float f) {
  union { float f; unsigned int i; } v; v.f = f;
  unsigned int x = v.i;
  x += 0x7fffu + ((x >> 16) & 1u);
  return (u16)(x >> 16);
}
// fast tanh: 1 - 2/(e^{2x}+1). Large +x: e=inf -> 1; large -x: e=0 -> -1.
__device__ __forceinline__ float ftanh(float x) {
  float e = __expf(2.f * x);
  return 1.f - 2.f / (e + 1.f);
}

// ---------------------------------------------------------------------------
// XCD-aware blockIdx remap (T1, m204 bijective form), 2D form for uniform
// grids (gemm_A / fallback gemm_bt).
// ---------------------------------------------------------------------------
__device__ __forceinline__ void xcd_remap(int axis, int& bx, int& by) {
  const int nx = gridDim.x, ny = gridDim.y;
  const int nwg = nx * ny;
  const int bid = blockIdx.x + nx * blockIdx.y;
  const int q = nwg >> 3, r = nwg & 7;
  const int xcd = bid & 7, i = bid >> 3;
  const int rem = (xcd < r ? xcd * (q + 1) : r * (q + 1) + (xcd - r) * q) + i;
  if (axis == 0) { bx = rem / ny; by = rem - bx * ny; }
  else           { by = rem / nx; bx = rem - by * nx; }
}

// 1D variant over the FULL-TILE range only (r15): bid in [0, nwg) -> (bx,by).
// Used by the fulls-first grids: the first 768 bids (3 blocks/CU static
// capacity) are all uniform full-K tiles -> equal static loads; remaining
// fulls + K=192 shorts are appended AFTER and get assigned dynamically to
// CUs as they free (HW work-stealing) -> near-balanced makespan.
// r14 post-mortem: sustained rate is ~520-545 TF in EVERY geometry tried;
// the 93-107us spread is busiest-CU quantization (6.3 vs 4.9 FBE). This
// ordering targets the 4.9-FBE floor (~79us for the step GEMM).
__device__ __forceinline__ void xcd_remap1d(int bid, int nwg, int ny, int& bx, int& by) {
  const int q = nwg >> 3, r = nwg & 7;
  const int xcd = bid & 7, i = bid >> 3;
  const int rem = (xcd < r ? xcd * (q + 1) : r * (q + 1) + (xcd - r) * q) + i;
  bx = rem / ny; by = rem - bx * ny;
}

// ---------------------------------------------------------------------------
// One-shot prep: every bf16 conversion + the prev matrix P, in ONE dispatch.
// P[32768][192]: row = t*2048 + e*128 + b, tt = e*16 + t;
// P[row][k] = (tt>0 && k<130) ? target[b][tt-1][k] : 0.
// ---------------------------------------------------------------------------
__global__ void mega_prep(const float* __restrict__ c, const float* __restrict__ fiw,
                          const float* __restrict__ g1whh, const float* __restrict__ g2wih,
                          const float* __restrict__ g2whh, const float* __restrict__ g1wih,
                          const float* __restrict__ fcow, const float* __restrict__ target,
                          u16* __restrict__ cbf, u16* __restrict__ Wfi, u16* __restrict__ W1h,
                          u16* __restrict__ W2i, u16* __restrict__ W2h, u16* __restrict__ Wc,
                          u16* __restrict__ Wd, u16* __restrict__ WBy, u16* __restrict__ P)
{
  int i = blockIdx.x * 256 + threadIdx.x;       // 57600 blocks x 256 = 14,745,600
  if (i < 1048576) { cbf[i] = f2b(c[i]); return; }
  i -= 1048576;
  if (i < 1048576) { Wfi[i] = f2b(fiw[i]); return; }
  i -= 1048576;
  if (i < 3145728) { W1h[i] = f2b(g1whh[i]); return; }
  i -= 3145728;
  if (i < 3145728) { W2i[i] = f2b(g2wih[i]); return; }
  i -= 3145728;
  if (i < 3145728) { W2h[i] = f2b(g2whh[i]); return; }
  i -= 3145728;
  if (i < 1572864) { int n = i >> 9, k = i & 511; Wc[i] = f2b(g1wih[n * 642 + k]); return; }
  i -= 1572864;
  if (i < 589824) {  // Wd [3072][192], zero-pad k>=130
    int n = i / 192, k = i - n * 192;
    Wd[i] = (k < 130) ? f2b(g1wih[n * 642 + 512 + k]) : (u16)0;
    return;
  }
  i -= 589824;
  if (i < 262144) { int n = i >> 10; WBy[i] = (n < 130) ? f2b(fcow[i]) : (u16)0; return; }
  i -= 262144;
  {  // P: 786432 items, 8 elems each
    int row = i / 24;
    int k0 = (i - row * 24) * 8;
    int t = row >> 11, m2 = row & 2047;
    int e = m2 >> 7, b = m2 & 127;
    int tt = e * 16 + t;
    u16x8 r;
    if (tt > 0 && k0 + 8 <= 130) {
      const float* trow = target + (size_t)(b * 256 + tt - 1) * 130 + k0;
#pragma unroll
      for (int q = 0; q < 8; ++q) r[q] = f2b(trow[q]);
    } else if (tt > 0 && k0 < 130) {
      const float* trow = target + (size_t)(b * 256 + tt - 1) * 130;
#pragma unroll
      for (int q = 0; q < 8; ++q) { int k = k0 + q; r[q] = (k < 130) ? f2b(trow[k]) : (u16)0; }
    } else {
#pragma unroll
      for (int q = 0; q < 8; ++q) r[q] = (u16)0;
    }
    *(u16x8*)&P[(size_t)row * 192 + k0] = r;
  }
}

// ---------------------------------------------------------------------------
// GEMM core — r13-verified geometry (best sustained: 543 TF): 128x128 tile,
// BK=32, 512 threads = 8 waves (4m x 2n of 32m x 64n, acc 2x4), mfma
// 16x16x32 bf16, f32 accum. 3-buffer counted-vmcnt K-loop (vmcnt(2));
// both-sides XOR swizzle (chunk' = chunk ^ ((row>>1)&3)) -> 0 conflicts.
// r14's 256x128 variant reverted (same sustained rate, worse balance).
// ---------------------------------------------------------------------------
__device__ __forceinline__ void kloop3(
    const u16* gA, const u16* gB, int nk,
    u16* AsBase, u16* BsBase, int wave,
    int rdA, int rdB, f32x4 (&acc)[2][4])
{
  u16* Adst = AsBase + wave * 512;   // per-wave 16-row slab, linear dest
  u16* Bdst = BsBase + wave * 512;
  gl16(gA,      Adst);        gl16(gB,      Bdst);
  gl16(gA + 32, Adst + 4096); gl16(gB + 32, Bdst + 4096);
  const u16* pA = gA + 64;
  const u16* pB = gB + 64;
  int cbuf = 0, nbuf = 2;
  for (int ks = 0; ks < nk; ++ks) {
    if (ks < nk - 1) asm volatile("s_waitcnt vmcnt(2)" : : : "memory");
    else             asm volatile("s_waitcnt vmcnt(0)" : : : "memory");
    __builtin_amdgcn_s_barrier();
    __builtin_amdgcn_sched_barrier(0);
    if (ks + 2 < nk) {
      gl16(pA, Adst + nbuf * 4096);
      gl16(pB, Bdst + nbuf * 4096);
      pA += 32; pB += 32;
    }
    const u16* Ab = AsBase + cbuf * 4096;
    const u16* Bb = BsBase + cbuf * 4096;
    frag8 af[2], bfr[4];
#pragma unroll
    for (int i = 0; i < 2; ++i)
      af[i] = *(const frag8*)&Ab[rdA + i * 512];
#pragma unroll
    for (int j = 0; j < 4; ++j)
      bfr[j] = *(const frag8*)&Bb[rdB + j * 512];
#pragma unroll
    for (int i = 0; i < 2; ++i)
#pragma unroll
      for (int j = 0; j < 4; ++j)
        acc[i][j] = __builtin_amdgcn_mfma_f32_16x16x32_bf16(af[i], bfr[j], acc[i][j], 0, 0, 0);
    cbuf = (cbuf == 2) ? 0 : cbuf + 1;
    nbuf = (nbuf == 2) ? 0 : nbuf + 1;
  }
}

// fragment-read / staging offsets shared by all GEMM kernels
struct GeomT { int wave, lane, wm, wn, lr, lq, rdA, rdB, srow, scol; };
__device__ __forceinline__ GeomT geom(int tid) {
  GeomT g;
  g.wave = tid >> 6; g.lane = tid & 63;
  g.wm = (g.wave & 3) * 32; g.wn = (g.wave >> 2) * 64;
  g.lr = g.lane & 15; g.lq = g.lane >> 4;
  int sw = (g.lr >> 1) & 3;
  g.rdA = (g.wm + g.lr) * 32 + ((g.lq ^ sw) << 3);
  g.rdB = (g.wn + g.lr) * 32 + ((g.lq ^ sw) << 3);
  g.srow = g.wave * 16 + (g.lane >> 2);
  g.scol = (((g.lane & 3) ^ ((g.lane >> 3) & 3)) << 3);
  return g;
}

// ---------------------------------------------------------------------------
// bt-GEMM (FALLBACK path only): modes 2/3/4.
// ---------------------------------------------------------------------------
__global__ __launch_bounds__(512, 6) void gemm_bt(
    const u16* __restrict__ A, int lda,
    const u16* __restrict__ B0, const u16* __restrict__ B1, int ldb, int n_split,
    int N, int K, int mode, int tstep, int axis,
    const float* __restrict__ bias0, const float* __restrict__ bias1,
    u16* __restrict__ out0, u16* __restrict__ out1,
    const u16* __restrict__ addmat,
    float* __restrict__ fout0, float* __restrict__ fout1)
{
  __shared__ u16 As[3 * 4096];
  __shared__ u16 Bs[3 * 4096];
  int bx, by; xcd_remap(axis, bx, by);
  GeomT g = geom(threadIdx.x);
  const int m0 = by * 128, n0 = bx * 128;

  const u16* Bsel; int nb0;
  if (n0 < n_split) { Bsel = B0; nb0 = n0; }
  else              { Bsel = B1; nb0 = n0 - n_split; }

  f32x4 acc[2][4] = {};
  const u16* gA = &A[(size_t)(m0 + g.srow) * lda + g.scol];
  const u16* gB = &Bsel[(size_t)(nb0 + g.srow) * ldb + g.scol];
  kloop3(gA, gB, K >> 5, As, Bs, g.wave, g.rdA, g.rdB, acc);

#pragma unroll
  for (int i = 0; i < 2; ++i) {
#pragma unroll
    for (int r = 0; r < 4; ++r) {
      int m = m0 + g.wm + i * 16 + g.lq * 4 + r;
#pragma unroll
      for (int j = 0; j < 4; ++j) {
        int n = n0 + g.wn + j * 16 + g.lr;
        float v = acc[i][j][r];
        if (mode == 2) {
          out0[(size_t)m * 3072 + n] = f2b(v + b2f(addmat[(size_t)(m & 2047) * 3072 + n]));
        } else if (mode == 3) {
          if (n < 3072) out0[(size_t)m * 3072 + n] = f2b(v + bias0[n]);
          else          out1[(size_t)m * 3072 + (n - 3072)] = f2b(v + bias1[n - 3072]);
        } else { // mode 4
          if (n < 3072) {
            out0[(size_t)m * 3072 + n] = f2b(v + bias0[n]);
          } else if (n < 3202) {
            int d = n - 3072;
            int b = m & 127, e = m >> 7;
            fout0[(size_t)((b << 8) + (e << 4) + tstep) * 130 + d] = v + bias1[d];
          }
        }
      }
    }
  }
}

// ---------------------------------------------------------------------------
// Init GEMM A: bx<16: {h1,h2} = tanh(c@Wfi.T + fib) (f32 + bf16 shadow);
// bx in [16,40): gic = c@Wc.T + g1bih.  Both K=512, A=cbf. Grid (40,16)
// = 640 blocks < 768: single round, uniform tiles, keep 2D remap.
// ---------------------------------------------------------------------------
__global__ __launch_bounds__(512, 6) void gemm_A(
    const u16* __restrict__ cbf, const u16* __restrict__ Wfi, const u16* __restrict__ Wc,
    const float* __restrict__ fib, const float* __restrict__ g1bih,
    float* __restrict__ h1f, float* __restrict__ h2f,
    u16* __restrict__ h1b, u16* __restrict__ h2b, u16* __restrict__ gic)
{
  __shared__ u16 As[3 * 4096];
  __shared__ u16 Bs[3 * 4096];
  int bx, by; xcd_remap(0, bx, by);
  GeomT g = geom(threadIdx.x);
  const int m0 = by * 128;
  const int isInit = (bx < 16);
  const int nb0 = isInit ? bx * 128 : (bx - 16) * 128;
  const u16* Bw = isInit ? Wfi : Wc;

  f32x4 acc[2][4] = {};
  const u16* gA = &cbf[(size_t)(m0 + g.srow) * 512 + g.scol];
  const u16* gB = &Bw[(size_t)(nb0 + g.srow) * 512 + g.scol];
  kloop3(gA, gB, 16, As, Bs, g.wave, g.rdA, g.rdB, acc);

#pragma unroll
  for (int i = 0; i < 2; ++i) {
#pragma unroll
    for (int r = 0; r < 4; ++r) {
      int m = m0 + g.wm + i * 16 + g.lq * 4 + r;
#pragma unroll
      for (int j = 0; j < 4; ++j) {
        int n = nb0 + g.wn + j * 16 + g.lr;
        float v = acc[i][j][r];
        if (isInit) {
          float t = ftanh(v + fib[n]);
          if (n < 1024) { h1f[(size_t)m * 1024 + n] = t;          h1b[(size_t)m * 1024 + n] = f2b(t); }
          else          { h2f[(size_t)m * 1024 + (n - 1024)] = t; h2b[(size_t)m * 1024 + (n - 1024)] = f2b(t); }
        } else {
          gic[(size_t)m * 3072 + n] = f2b(v + g1bih[n]);
        }
      }
    }
  }
}

// ---------------------------------------------------------------------------
// Init GEMM B (r15: 1D fulls-first): bids [0,768) = fulls via remap1d
// (bx<24: gh1 = h1@W1h+b1hh | bx<48: gh2 = h2@W2h+b2hh, K=1024);
// bids [768, 768+nshort) = gi1(0) = P[t=0]@Wd.T + gic (K=192), appended
// so the dynamic tail self-balances. Fallback: grid 768 (no shorts).
// ---------------------------------------------------------------------------
__global__ __launch_bounds__(512, 6) void gemm_B(
    const u16* __restrict__ h1b, const u16* __restrict__ h2b, const u16* __restrict__ P,
    const u16* __restrict__ W1h, const u16* __restrict__ W2h, const u16* __restrict__ Wd,
    const float* __restrict__ b1hh, const float* __restrict__ b2hh,
    const u16* __restrict__ gic,
    u16* __restrict__ gh1, u16* __restrict__ gh2, u16* __restrict__ gi1w)
{
  __shared__ u16 As[3 * 4096];
  __shared__ u16 Bs[3 * 4096];
  GeomT g = geom(threadIdx.x);
  const int bid = blockIdx.x;
  const int NF = 48 * 16;
  int reg, nb0, m0, ld, K;
  const u16 *A, *Bw;
  if (bid < NF) {
    int bx, by; xcd_remap1d(bid, NF, 16, bx, by);
    m0 = by * 128;
    if (bx < 24) { reg = 0; nb0 = bx * 128;        A = h1b; Bw = W1h; }
    else         { reg = 1; nb0 = (bx - 24) * 128; A = h2b; Bw = W2h; }
    ld = 1024; K = 1024;
  } else {
    int s = bid - NF;
    reg = 2; nb0 = (s >> 4) * 128; m0 = (s & 15) * 128;
    A = P; Bw = Wd; ld = 192; K = 192;
  }

  f32x4 acc[2][4] = {};
  const u16* gA = &A[(size_t)(m0 + g.srow) * ld + g.scol];
  const u16* gB = &Bw[(size_t)(nb0 + g.srow) * ld + g.scol];
  kloop3(gA, gB, K >> 5, As, Bs, g.wave, g.rdA, g.rdB, acc);

#pragma unroll
  for (int i = 0; i < 2; ++i) {
#pragma unroll
    for (int r = 0; r < 4; ++r) {
      int m = m0 + g.wm + i * 16 + g.lq * 4 + r;
#pragma unroll
      for (int j = 0; j < 4; ++j) {
        int n = nb0 + g.wn + j * 16 + g.lr;
        float v = acc[i][j][r];
        if (reg == 0)      gh1[(size_t)m * 3072 + n] = f2b(v + b1hh[n]);
        else if (reg == 1) gh2[(size_t)m * 3072 + n] = f2b(v + b2hh[n]);
        else               gi1w[(size_t)m * 3072 + n] = f2b(v + b2f(gic[(size_t)m * 3072 + n]));
      }
    }
  }
}

// ---------------------------------------------------------------------------
// Fused step GEMM, r15 1D fulls-first layout.
// FULL tiles (K=1024), bid < nfx*16, region by bx (c0,c1,c2 thresholds):
//   [0,c0)   reg0 gi2  = h1@W2i + b_gi2
//   [c0,c1)  reg1 gh1' = h1@W1h + b_gh1
//   [c1,c2)  reg2 gh2' = h2@W2h + b_gh2
//   [c2,nfx) reg3 y(tstep) = h2@WBy + fcob, f32 scatter (cols<130)
// SHORT tiles (K=192), bid >= nfx*16: reg4 gi1(t+1) = Pt@Wd.T + gic -> g1A.
// Fulls-first: first 768 bids = uniform static round; tail dynamic.
// Configs (nfx, nshort, c0,c1,c2):
//   G(0)     = (48, 24, 24,48,48)   gi2, gh1', gi1(1)
//   G(1..14) = (74, 24, 24,48,72)   all five
//   G(15)    = (50,  0, 24,24,48)   gi2(15), gh2(15), y(14)  [r13 fix kept]
//   G(16)    = ( 2,  0,  0, 0, 0)   y(15) only
// Rolling g1A safe: C(t) reads strictly before G(t) overwrites (same stream).
// ---------------------------------------------------------------------------
__global__ __launch_bounds__(512, 6) void gemm_fused(
    const u16* __restrict__ h1b, const u16* __restrict__ h2b, const u16* __restrict__ Pt,
    const u16* __restrict__ W2i, const u16* __restrict__ W1h, const u16* __restrict__ W2h,
    const u16* __restrict__ WBy, const u16* __restrict__ Wd,
    const float* __restrict__ b_gi2, const float* __restrict__ b_gh1,
    const float* __restrict__ b_gh2, const float* __restrict__ b_y,
    const u16* __restrict__ gic,
    u16* __restrict__ gi2, u16* __restrict__ gh1, u16* __restrict__ gh2,
    float* __restrict__ y, u16* __restrict__ gi1w,
    int c0, int c1, int c2, int nfx, int tstep)
{
  __shared__ u16 As[3 * 4096];
  __shared__ u16 Bs[3 * 4096];
  GeomT g = geom(threadIdx.x);
  const int bid = blockIdx.x;
  const int NF = nfx * 16;
  int reg, nb0, m0, ld, K;
  const u16 *A, *Bw;
  if (bid < NF) {
    int bx, by; xcd_remap1d(bid, NF, 16, bx, by);
    m0 = by * 128;
    if (bx < c0)      { reg = 0; nb0 = bx * 128;        A = h1b; Bw = W2i; }
    else if (bx < c1) { reg = 1; nb0 = (bx - c0) * 128; A = h1b; Bw = W1h; }
    else if (bx < c2) { reg = 2; nb0 = (bx - c1) * 128; A = h2b; Bw = W2h; }
    else              { reg = 3; nb0 = (bx - c2) * 128; A = h2b; Bw = WBy; }
    ld = 1024; K = 1024;
  } else {
    int s = bid - NF;
    reg = 4; nb0 = (s >> 4) * 128; m0 = (s & 15) * 128;
    A = Pt; Bw = Wd; ld = 192; K = 192;
  }

  f32x4 acc[2][4] = {};
  const u16* gA = &A[(size_t)(m0 + g.srow) * ld + g.scol];
  const u16* gB = &Bw[(size_t)(nb0 + g.srow) * ld + g.scol];
  kloop3(gA, gB, K >> 5, As, Bs, g.wave, g.rdA, g.rdB, acc);

#pragma unroll
  for (int i = 0; i < 2; ++i) {
#pragma unroll
    for (int r = 0; r < 4; ++r) {
      int m = m0 + g.wm + i * 16 + g.lq * 4 + r;
#pragma unroll
      for (int j = 0; j < 4; ++j) {
        int nl = nb0 + g.wn + j * 16 + g.lr;
        float v = acc[i][j][r];
        if (reg == 0)      gi2[(size_t)m * 3072 + nl] = f2b(v + b_gi2[nl]);
        else if (reg == 1) gh1[(size_t)m * 3072 + nl] = f2b(v + b_gh1[nl]);
        else if (reg == 2) gh2[(size_t)m * 3072 + nl] = f2b(v + b_gh2[nl]);
        else if (reg == 3) {
          if (nl < 130) {
            int b = m & 127, e = m >> 7;
            y[(size_t)((b << 8) + (e << 4) + tstep) * 130 + nl] = v + b_y[nl];
          }
        } else {
          gi1w[(size_t)m * 3072 + nl] = f2b(v + b2f(gic[(size_t)m * 3072 + nl]));
        }
      }
    }
  }
}

// ---------------------------------------------------------------------------
// Fused GRU combine: slot A = combine1(t) [h1 <- GRU1], slot B =
// combine2(t-1) [h2 <- GRU2]. h = (1-z)*n + z*h; gi/gh bf16 [2048,3072]
// (biases folded), h32 f32 master state (in place), hb16 bf16 shadow.
// ---------------------------------------------------------------------------
__global__ __launch_bounds__(256) void gru2(
    const u16* __restrict__ giA, const u16* __restrict__ ghA,
    float* __restrict__ hA, u16* __restrict__ hbA,
    const u16* __restrict__ giB, const u16* __restrict__ ghB,
    float* __restrict__ hB, u16* __restrict__ hbB,
    int doA, int doB)
{
  int blk = blockIdx.x;
  const u16 *gi, *gh; float* h32; u16* hb16;
  if (blk < 1024) { if (!doA) return; gi = giA; gh = ghA; h32 = hA; hb16 = hbA; }
  else { if (!doB) return; gi = giB; gh = ghB; h32 = hB; hb16 = hbB; blk -= 1024; }
  int idx = blk * 256 + threadIdx.x;   // 0 .. 2048*128-1
  int m = idx >> 7;
  int j0 = (idx & 127) << 3;
  const size_t gb = (size_t)m * 3072 + j0;
  const size_t hb = (size_t)m * 1024 + j0;
  u16x8 ir = *(const u16x8*)&gi[gb];
  u16x8 iz = *(const u16x8*)&gi[gb + 1024];
  u16x8 in_ = *(const u16x8*)&gi[gb + 2048];
  u16x8 hr = *(const u16x8*)&gh[gb];
  u16x8 hz = *(const u16x8*)&gh[gb + 1024];
  u16x8 hn = *(const u16x8*)&gh[gb + 2048];
  f32x4 h0 = *(const f32x4*)&h32[hb];
  f32x4 h1v = *(const f32x4*)&h32[hb + 4];
  f32x4 o0, o1;
  u16x8 ob;
#pragma unroll
  for (int q = 0; q < 8; ++q) {
    float r = 1.f / (1.f + __expf(-(b2f(ir[q]) + b2f(hr[q]))));
    float z = 1.f / (1.f + __expf(-(b2f(iz[q]) + b2f(hz[q]))));
    float nn = ftanh(b2f(in_[q]) + r * b2f(hn[q]));
    float hh = (q < 4) ? h0[q & 3] : h1v[q & 3];
    float res = (1.f - z) * nn + z * hh;
    if (q < 4) o0[q & 3] = res; else o1[q & 3] = res;
    ob[q] = f2b(res);
  }
  *(f32x4*)&h32[hb] = o0;
  *(f32x4*)&h32[hb + 4] = o1;
  *(u16x8*)&hb16[hb] = ob;
}

// ---------------------------------------------------------------------------
extern "C" void kernel_launch(void* const* d_in, const int* in_sizes, int n_in,
                              void* d_out, int out_size, void* d_ws, size_t ws_size,
                              hipStream_t stream)
{
  const float* c      = (const float*)d_in[0];
  const float* target = (const float*)d_in[1];
  const float* fiw    = (const float*)d_in[4];
  const float* fib    = (const float*)d_in[5];
  const float* g1wih  = (const float*)d_in[6];
  const float* g1whh  = (const float*)d_in[7];
  const float* g1bih  = (const float*)d_in[8];
  const float* g1bhh  = (const float*)d_in[9];
  const float* g2wih  = (const float*)d_in[10];
  const float* g2whh  = (const float*)d_in[11];
  const float* g2bih  = (const float*)d_in[12];
  const float* g2bhh  = (const float*)d_in[13];
  const float* fcow   = (const float*)d_in[14];
  const float* fcob   = (const float*)d_in[15];
  float* out = (float*)d_out;

  char* wsp = (char*)d_ws;
  size_t off = 0;
  auto takeb = [&](size_t bytes) {
    void* p = (void*)(wsp + off);
    off += bytes;
    off = (off + 255) & ~(size_t)255;
    return p;
  };
  float* h1f = (float*)takeb((size_t)2048 * 1024 * 4);
  float* h2f = (float*)takeb((size_t)2048 * 1024 * 4);
  u16* h1b   = (u16*)takeb((size_t)2048 * 1024 * 2);
  u16* h2b   = (u16*)takeb((size_t)2048 * 1024 * 2);
  u16* gic   = (u16*)takeb((size_t)2048 * 3072 * 2);
  u16* gib   = (u16*)takeb((size_t)2048 * 3072 * 2);
  u16* gh1   = (u16*)takeb((size_t)2048 * 3072 * 2);
  u16* gh2   = (u16*)takeb((size_t)2048 * 3072 * 2);
  u16* cbf   = (u16*)takeb((size_t)2048 * 512 * 2);
  u16* Wfi   = (u16*)takeb((size_t)2048 * 512 * 2);
  u16* Wc    = (u16*)takeb((size_t)3072 * 512 * 2);
  u16* Wd    = (u16*)takeb((size_t)3072 * 192 * 2);
  u16* W1h   = (u16*)takeb((size_t)3072 * 1024 * 2);
  u16* W2i   = (u16*)takeb((size_t)3072 * 1024 * 2);
  u16* W2h   = (u16*)takeb((size_t)3072 * 1024 * 2);
  u16* WBy   = (u16*)takeb((size_t)256 * 1024 * 2);
  u16* P     = (u16*)takeb((size_t)32768 * 192 * 2);   // prev matrix, all t
  // base ~116 MiB. Rolling gi1 buffer (12.6 MiB) for the fast path.
  u16* g1A = nullptr;
  if (ws_size >= off + (size_t)2048 * 3072 * 2 + 256) g1A = (u16*)takeb((size_t)2048 * 3072 * 2);
  (void)in_sizes; (void)n_in; (void)out_size;

  const int BIG = 1 << 30;

  // --- prep + init ---
  mega_prep<<<57600, 256, 0, stream>>>(c, fiw, g1whh, g2wih, g2whh, g1wih, fcow, target,
                                       cbf, Wfi, W1h, W2i, W2h, Wc, Wd, WBy, P);
  gemm_A<<<dim3(40, 16), 512, 0, stream>>>(cbf, Wfi, Wc, fib, g1bih,
                                           h1f, h2f, h1b, h2b, gic);

  if (g1A != nullptr) {
    // gh1 | gh2 (768 fulls) + gi1(0) (384 shorts)
    gemm_B<<<768 + 384, 512, 0, stream>>>(h1b, h2b, P, W1h, W2h, Wd,
                                          g1bhh, g2bhh, gic, gh1, gh2, g1A);
    // C(0): combine1(0)
    gru2<<<2048, 256, 0, stream>>>(g1A, gh1, h1f, h1b, nullptr, nullptr, nullptr, nullptr, 1, 0);
    // G(0): gi2(0), gh1'(1) fulls + gi1(1) shorts
    gemm_fused<<<48 * 16 + 24 * 16, 512, 0, stream>>>(h1b, h2b, P + (size_t)1 * 2048 * 192,
                                                      W2i, W1h, W2h, WBy, Wd,
                                                      g2bih, g1bhh, g2bhh, fcob, gic,
                                                      gib, gh1, gh2, out, g1A,
                                                      24, 48, 48, 48, 0);
    for (int t = 1; t <= 14; ++t) {
      // C(t): combine1(t) [g1A, gh1] + combine2(t-1) [gib, gh2]
      gru2<<<2048, 256, 0, stream>>>(g1A, gh1, h1f, h1b, gib, gh2, h2f, h2b, 1, 1);
      // G(t): gi2(t), gh1'(t+1), gh2'(t), y(t-1) fulls + gi1(t+1) shorts
      gemm_fused<<<74 * 16 + 24 * 16, 512, 0, stream>>>(h1b, h2b, P + (size_t)(t + 1) * 2048 * 192,
                                                        W2i, W1h, W2h, WBy, Wd,
                                                        g2bih, g1bhh, g2bhh, fcob, gic,
                                                        gib, gh1, gh2, out, g1A,
                                                        24, 48, 72, 74, t - 1);
    }
    // C(15): combine1(15) + combine2(14)
    gru2<<<2048, 256, 0, stream>>>(g1A, gh1, h1f, h1b, gib, gh2, h2f, h2b, 1, 1);
    // G(15): gi2(15) + gh2(15) + y(14), no shorts
    gemm_fused<<<50 * 16, 512, 0, stream>>>(h1b, h2b, P,
                                            W2i, W1h, W2h, WBy, Wd,
                                            g2bih, g1bhh, g2bhh, fcob, gic,
                                            gib, gh1, gh2, out, g1A,
                                            24, 24, 48, 50, 14);
    // C(16): combine2(15)
    gru2<<<2048, 256, 0, stream>>>(nullptr, nullptr, nullptr, nullptr,
                                   gib, gh2, h2f, h2b, 0, 1);
    // G(16): y(15) only
    gemm_fused<<<2 * 16, 512, 0, stream>>>(h1b, h2b, P,
                                           W2i, W1h, W2h, WBy, Wd,
                                           g2bih, g1bhh, g2bhh, fcob, gic,
                                           gib, gh1, gh2, out, g1A,
                                           0, 0, 0, 2, 15);
  } else {
    // fallback (tiny ws): per-step sequence; gh1/gh2 init via gemm_B fulls only
    gemm_B<<<768, 512, 0, stream>>>(h1b, h2b, P, W1h, W2h, Wd,
                                    g1bhh, g2bhh, gic, gh1, gh2, nullptr);
    for (int t = 0; t < 16; ++t) {
      gemm_bt<<<dim3(24, 16), 512, 0, stream>>>(P + (size_t)t * 2048 * 192, 192, Wd, nullptr, 192, BIG,
                                                3072, 192, 2, 0, 0, nullptr, nullptr,
                                                gib, nullptr, gic, nullptr, nullptr);
      gru2<<<2048, 256, 0, stream>>>(gib, gh1, h1f, h1b, nullptr, nullptr, nullptr, nullptr, 1, 0);
      gemm_bt<<<dim3(48, 16), 512, 0, stream>>>(h1b, 1024, W2i, W1h, 1024, 3072,
                                                6144, 1024, 3, 0, 0, g2bih, g1bhh,
                                                gib, gh1, nullptr, nullptr, nullptr);
      gru2<<<2048, 256, 0, stream>>>(gib, gh2, h2f, h2b, nullptr, nullptr, nullptr, nullptr, 1, 0);
      gemm_bt<<<dim3(26, 16), 512, 0, stream>>>(h2b, 1024, W2h, WBy, 1024, 3072,
                                                3328, 1024, 4, t, 0, g2bhh, fcob,
                                                gh2, nullptr, nullptr, out, nullptr);
    }
  }
}